// Round 1
// baseline (356.233 us; speedup 1.0000x reference)
//
#include <hip/hip_runtime.h>

typedef __attribute__((ext_vector_type(8))) short bf16x8;
typedef __attribute__((ext_vector_type(4))) float f32x4;

#define DEVICE __device__ __forceinline__

static constexpr int Tc = 2048;     // seq len
static constexpr int Dc = 2048;     // model dim
static constexpr int Hc = 16;       // heads
static constexpr int HD = 128;      // head dim
static constexpr int MR = 4096;     // B*T rows
static constexpr int NQKV = 6144;   // 3*D

DEVICE float bf2f(unsigned short u) {
  unsigned int t = ((unsigned int)u) << 16;
  float f; __builtin_memcpy(&f, &t, 4); return f;
}
DEVICE unsigned short f2bf(float f) {
  unsigned int t; __builtin_memcpy(&t, &f, 4);
  unsigned int r = (t + 0x7fffu + ((t >> 16) & 1u)) >> 16;
  return (unsigned short)r;
}

DEVICE void async_cp16(const void* g, void* lds) {
  __builtin_amdgcn_global_load_lds((const __attribute__((address_space(1))) void*)g,
                                   (__attribute__((address_space(3))) void*)lds, 16, 0, 0);
}

// ---------------- RoPE cos/sin table: cs[t][j] = (cos, sin), j in [0,64) ----
__global__ void rope_table_kernel(float2* cs) {
  int t = blockIdx.x;
  int j = threadIdx.x;                   // 0..63
  float inv = powf(10000.0f, -(float)(2 * j) / 128.0f);
  float ang = (float)t * inv;
  cs[t * 64 + j] = make_float2(cosf(ang), sinf(ang));
}

// ---------------- fp32 -> bf16 elementwise (vectorized) ---------------------
__global__ void f32_to_bf16_kernel(const float* __restrict__ in,
                                   unsigned short* __restrict__ out, int n) {
  int i = (blockIdx.x * blockDim.x + threadIdx.x) * 4;
  if (i >= n) return;
  float4 v = *(const float4*)(in + i);
  ushort4 o;
  o.x = f2bf(v.x); o.y = f2bf(v.y); o.z = f2bf(v.z); o.w = f2bf(v.w);
  *(ushort4*)(out + i) = o;
}

// ---------------- transpose fp32 (R x C) -> bf16 (C x R) --------------------
__global__ void transpose_f32_bf16_kernel(const float* __restrict__ in,
                                          unsigned short* __restrict__ out,
                                          int R, int C) {
  __shared__ float tile[32][33];
  int c0 = blockIdx.x * 32, r0 = blockIdx.y * 32;
  int tx = threadIdx.x, ty = threadIdx.y;
#pragma unroll
  for (int i = 0; i < 4; ++i)
    tile[ty + i * 8][tx] = in[(size_t)(r0 + ty + i * 8) * C + c0 + tx];
  __syncthreads();
#pragma unroll
  for (int i = 0; i < 4; ++i)
    out[(size_t)(c0 + ty + i * 8) * R + r0 + tx] = f2bf(tile[tx][ty + i * 8]);
}

// ---------------- bf16 transpose of V slice: qkvb cols[4096..6144) ----------
// out vt[(bh*128 + d)*T + t]
__global__ void v_transpose_kernel(const unsigned short* __restrict__ qkvb,
                                   unsigned short* __restrict__ vt) {
  __shared__ unsigned short tile[32][33];
  int t0 = blockIdx.x * 32, d0 = blockIdx.y * 32, bh = blockIdx.z;
  int b = bh >> 4, h = bh & 15;
  int tx = threadIdx.x, ty = threadIdx.y;
#pragma unroll
  for (int i = 0; i < 4; ++i) {
    int t = t0 + ty + i * 8;
    tile[ty + i * 8][tx] =
        qkvb[(size_t)(b * Tc + t) * NQKV + 2 * Dc + h * HD + d0 + tx];
  }
  __syncthreads();
#pragma unroll
  for (int i = 0; i < 4; ++i) {
    int d = d0 + ty + i * 8;
    vt[(size_t)(bh * HD + d) * Tc + t0 + tx] = tile[tx][ty + i * 8];
  }
}

// ---------------- RoPE apply: qkvb -> qh, kh in (B,H,T,Hd) ------------------
__global__ void rope_apply_kernel(const unsigned short* __restrict__ qkvb,
                                  const float2* __restrict__ cs,
                                  unsigned short* __restrict__ qh,
                                  unsigned short* __restrict__ kh) {
  int m = blockIdx.x;          // b*T + t
  int h = blockIdx.y;
  int j = threadIdx.x;         // 0..63
  int t = m & (Tc - 1);
  int b = m >> 11;
  float2 c = cs[t * 64 + j];
  size_t base = (size_t)m * NQKV + h * HD;
  float q1 = bf2f(qkvb[base + j]);
  float q2 = bf2f(qkvb[base + j + 64]);
  float k1 = bf2f(qkvb[base + Dc + j]);
  float k2 = bf2f(qkvb[base + Dc + j + 64]);
  size_t ob = ((size_t)(b * Hc + h) * Tc + t) * HD;
  qh[ob + j]      = f2bf(q1 * c.x - q2 * c.y);
  qh[ob + j + 64] = f2bf(q2 * c.x + q1 * c.y);
  kh[ob + j]      = f2bf(k1 * c.x - k2 * c.y);
  kh[ob + j + 64] = f2bf(k2 * c.x + k1 * c.y);
}

// ---------------- bf16 GEMM, B^T input: C[m][n] = sum_k A[m][k]*Bt[n][k] ----
// 128x128 tile, BK=64, 4 waves, each wave 64x64 (4x4 frags of 16x16x32).
DEVICE void cstore(unsigned short* p, float v) { *p = f2bf(v); }
DEVICE void cstore(float* p, float v) { *p = v; }

template <typename OutT>
__global__ __launch_bounds__(256, 2)
void gemm_bt_kernel(const unsigned short* __restrict__ A,
                    const unsigned short* __restrict__ Bt,
                    OutT* __restrict__ C, int M, int N, int K) {
  __shared__ unsigned short As[128 * 64];
  __shared__ unsigned short Bs[128 * 64];

  int nbx = N >> 7;
  int nwg = gridDim.x;
  int wg = blockIdx.x;
  int cpx = nwg >> 3;                 // grids are multiples of 8 -> bijective
  wg = (wg & 7) * cpx + (wg >> 3);
  int by = wg / nbx, bx = wg - by * nbx;
  int m0 = by << 7, n0 = bx << 7;

  int tid = threadIdx.x, lane = tid & 63, wid = tid >> 6;
  int wm = (wid >> 1) << 6, wn = (wid & 1) << 6;

  f32x4 acc[4][4] = {};

  for (int k0 = 0; k0 < K; k0 += 64) {
    __syncthreads();
#pragma unroll
    for (int r = 0; r < 4; ++r) {
      int p = r * 4096 + wid * 1024 + lane * 16;   // byte offset in tile
      int row = p >> 7;
      int cb = (p & 127) ^ ((row & 7) << 4);       // pre-swizzled source col
      const char* ga = (const char*)A + ((size_t)(m0 + row) * K + k0) * 2 + cb;
      async_cp16(ga, (char*)As + r * 4096 + wid * 1024);
      const char* gb = (const char*)Bt + ((size_t)(n0 + row) * K + k0) * 2 + cb;
      async_cp16(gb, (char*)Bs + r * 4096 + wid * 1024);
    }
    __syncthreads();

#pragma unroll
    for (int ks = 0; ks < 2; ++ks) {
      bf16x8 af[4], bfr[4];
#pragma unroll
      for (int mi = 0; mi < 4; ++mi) {
        int row = wm + mi * 16 + (lane & 15);
        int cb = (ks * 64 + ((lane >> 4) << 4)) ^ ((row & 7) << 4);
        af[mi] = *(const bf16x8*)((const char*)As + row * 128 + cb);
      }
#pragma unroll
      for (int ni = 0; ni < 4; ++ni) {
        int row = wn + ni * 16 + (lane & 15);
        int cb = (ks * 64 + ((lane >> 4) << 4)) ^ ((row & 7) << 4);
        bfr[ni] = *(const bf16x8*)((const char*)Bs + row * 128 + cb);
      }
#pragma unroll
      for (int mi = 0; mi < 4; ++mi)
#pragma unroll
        for (int ni = 0; ni < 4; ++ni)
          acc[mi][ni] = __builtin_amdgcn_mfma_f32_16x16x32_bf16(
              af[mi], bfr[ni], acc[mi][ni], 0, 0, 0);
    }
  }

#pragma unroll
  for (int mi = 0; mi < 4; ++mi)
#pragma unroll
    for (int ni = 0; ni < 4; ++ni)
#pragma unroll
      for (int r = 0; r < 4; ++r) {
        int row = m0 + wm + mi * 16 + ((lane >> 4) << 2) + r;
        int col = n0 + wn + ni * 16 + (lane & 15);
        cstore(C + (size_t)row * N + col, acc[mi][ni][r]);
      }
}

// ---------------- causal flash attention ------------------------------------
// grid (T/128, B*H), 4 waves. Each wave: 32 q-rows. BK=64.
__global__ __launch_bounds__(256, 2)
void attn_kernel(const unsigned short* __restrict__ qh,
                 const unsigned short* __restrict__ kh,
                 const unsigned short* __restrict__ vt,
                 unsigned short* __restrict__ ao) {
  const float scale = 0.08838834764831845f;  // 1/sqrt(128)
  int qt = blockIdx.x;
  int bh = blockIdx.y;
  int b = bh >> 4, h = bh & 15;

  __shared__ unsigned short Qs[128 * 128];   // 32KB, 256B rows, swizzled
  __shared__ unsigned short Ks[64 * 128];    // 16KB, 256B rows, swizzled
  __shared__ unsigned short Vs[128 * 64];    // 16KB, V^T: rows=d, 128B rows
  __shared__ unsigned short Ps[4][32 * 64];  // 16KB, per-wave P, 128B rows

  int tid = threadIdx.x, lane = tid & 63, wid = tid >> 6;

  const unsigned short* Qg = qh + ((size_t)bh * Tc + qt * 128) * HD;
  const unsigned short* Kg = kh + (size_t)bh * Tc * HD;
  const unsigned short* Vg = vt + (size_t)bh * HD * Tc;

  // stage Q tile (swizzled write)
#pragma unroll
  for (int r = 0; r < 8; ++r) {
    int p = r * 4096 + tid * 16;
    int row = p >> 8, cb = p & 255;
    bf16x8 v = *(const bf16x8*)((const char*)Qg + row * 256 + cb);
    *(bf16x8*)((char*)Qs + row * 256 + (cb ^ ((row & 7) << 4))) = v;
  }
  __syncthreads();

  // hoist Q fragments to registers
  bf16x8 qf[2][4];
#pragma unroll
  for (int mi = 0; mi < 2; ++mi)
#pragma unroll
    for (int ks = 0; ks < 4; ++ks) {
      int row = wid * 32 + mi * 16 + (lane & 15);
      int cb = (ks * 64 + ((lane >> 4) << 4)) ^ ((row & 7) << 4);
      qf[mi][ks] = *(const bf16x8*)((const char*)Qs + row * 256 + cb);
    }

  f32x4 oacc[2][8] = {};
  float mrow[2][4], lrow[2][4];
#pragma unroll
  for (int mi = 0; mi < 2; ++mi)
#pragma unroll
    for (int r = 0; r < 4; ++r) { mrow[mi][r] = -1e30f; lrow[mi][r] = 0.f; }

  int nkt = (qt + 1) * 2;
  for (int kt = 0; kt < nkt; ++kt) {
    __syncthreads();
    // stage K tile (64x128, 256B rows) + V^T tile (128x64, 128B rows)
#pragma unroll
    for (int r = 0; r < 4; ++r) {
      int p = r * 4096 + tid * 16;
      {
        int kr = p >> 8, cb = p & 255;
        bf16x8 v = *(const bf16x8*)((const char*)Kg +
                                    ((size_t)(kt * 64 + kr)) * 256 + cb);
        *(bf16x8*)((char*)Ks + kr * 256 + (cb ^ ((kr & 7) << 4))) = v;
      }
      {
        int d = p >> 7, cbt = p & 127;
        bf16x8 v = *(const bf16x8*)((const char*)Vg + (size_t)d * (Tc * 2) +
                                    kt * 128 + cbt);
        *(bf16x8*)((char*)Vs + d * 128 + (cbt ^ ((d & 7) << 4))) = v;
      }
    }
    __syncthreads();

    // S = Q K^T for this wave's 32 rows x 64 cols
    f32x4 sacc[2][4] = {};
#pragma unroll
    for (int ks = 0; ks < 4; ++ks) {
      bf16x8 kf[4];
#pragma unroll
      for (int ni = 0; ni < 4; ++ni) {
        int row = ni * 16 + (lane & 15);
        int cb = (ks * 64 + ((lane >> 4) << 4)) ^ ((row & 7) << 4);
        kf[ni] = *(const bf16x8*)((const char*)Ks + row * 256 + cb);
      }
#pragma unroll
      for (int mi = 0; mi < 2; ++mi)
#pragma unroll
        for (int ni = 0; ni < 4; ++ni)
          sacc[mi][ni] = __builtin_amdgcn_mfma_f32_16x16x32_bf16(
              qf[mi][ks], kf[ni], sacc[mi][ni], 0, 0, 0);
    }

    // online softmax (wave-parallel, 16-lane groups own 4 rows)
    bool diag = (kt >= 2 * qt);
    float pvv[2][4][4];
    float fsc[2][4];
#pragma unroll
    for (int mi = 0; mi < 2; ++mi) {
#pragma unroll
      for (int r = 0; r < 4; ++r) {
        int qrow = wid * 32 + mi * 16 + ((lane >> 4) << 2) + r;  // local row
        float sv[4];
        float mx = -1e30f;
#pragma unroll
        for (int ni = 0; ni < 4; ++ni) {
          float s = sacc[mi][ni][r] * scale;
          if (diag) {
            int kcol = kt * 64 + ni * 16 + (lane & 15);
            if (kcol > qt * 128 + qrow) s = -1e30f;
          }
          sv[ni] = s;
          mx = fmaxf(mx, s);
        }
        mx = fmaxf(mx, __shfl_xor(mx, 1));
        mx = fmaxf(mx, __shfl_xor(mx, 2));
        mx = fmaxf(mx, __shfl_xor(mx, 4));
        mx = fmaxf(mx, __shfl_xor(mx, 8));
        float mnew = fmaxf(mrow[mi][r], mx);
        float f = __expf(mrow[mi][r] - mnew);
        mrow[mi][r] = mnew;
        float ls = 0.f;
#pragma unroll
        for (int ni = 0; ni < 4; ++ni) {
          float pp = __expf(sv[ni] - mnew);
          pvv[mi][ni][r] = pp;
          ls += pp;
        }
        ls += __shfl_xor(ls, 1);
        ls += __shfl_xor(ls, 2);
        ls += __shfl_xor(ls, 4);
        ls += __shfl_xor(ls, 8);
        lrow[mi][r] = lrow[mi][r] * f + ls;
        fsc[mi][r] = f;
      }
    }
    // rescale O
#pragma unroll
    for (int mi = 0; mi < 2; ++mi)
#pragma unroll
      for (int nj = 0; nj < 8; ++nj)
#pragma unroll
        for (int r = 0; r < 4; ++r) oacc[mi][nj][r] *= fsc[mi][r];

    // write P (bf16) to per-wave LDS, swizzled
#pragma unroll
    for (int mi = 0; mi < 2; ++mi)
#pragma unroll
      for (int ni = 0; ni < 4; ++ni)
#pragma unroll
        for (int r = 0; r < 4; ++r) {
          int row = mi * 16 + ((lane >> 4) << 2) + r;
          int colb = (ni * 16 + (lane & 15)) * 2;
          *(unsigned short*)((char*)&Ps[wid][0] + row * 128 +
                             (colb ^ ((row & 7) << 4))) = f2bf(pvv[mi][ni][r]);
        }

    // O += P @ V  (same-wave LDS RAW; compiler inserts lgkmcnt waits)
#pragma unroll
    for (int ks = 0; ks < 2; ++ks) {
      bf16x8 pf[2];
#pragma unroll
      for (int mi = 0; mi < 2; ++mi) {
        int row = mi * 16 + (lane & 15);
        int cb = (ks * 64 + ((lane >> 4) << 4)) ^ ((row & 7) << 4);
        pf[mi] = *(const bf16x8*)((const char*)&Ps[wid][0] + row * 128 + cb);
      }
#pragma unroll
      for (int nj = 0; nj < 8; ++nj) {
        int row = nj * 16 + (lane & 15);
        int cb = (ks * 64 + ((lane >> 4) << 4)) ^ ((row & 7) << 4);
        bf16x8 vf = *(const bf16x8*)((const char*)Vs + row * 128 + cb);
#pragma unroll
        for (int mi = 0; mi < 2; ++mi)
          oacc[mi][nj] = __builtin_amdgcn_mfma_f32_16x16x32_bf16(
              pf[mi], vf, oacc[mi][nj], 0, 0, 0);
      }
    }
  }

  // epilogue: O / l -> ao (B,T,D) bf16
#pragma unroll
  for (int mi = 0; mi < 2; ++mi) {
    float inv[4];
#pragma unroll
    for (int r = 0; r < 4; ++r) inv[r] = 1.f / lrow[mi][r];
#pragma unroll
    for (int nj = 0; nj < 8; ++nj)
#pragma unroll
      for (int r = 0; r < 4; ++r) {
        int trow = qt * 128 + wid * 32 + mi * 16 + ((lane >> 4) << 2) + r;
        int col = nj * 16 + (lane & 15);
        ao[((size_t)(b * Tc + trow)) * Dc + h * HD + col] =
            f2bf(oacc[mi][nj][r] * inv[r]);
      }
  }
}

// ---------------- launcher --------------------------------------------------
extern "C" void kernel_launch(void* const* d_in, const int* in_sizes, int n_in,
                              void* d_out, int out_size, void* d_ws,
                              size_t ws_size, hipStream_t stream) {
  const float* x = (const float*)d_in[0];
  const float* w_qkv = (const float*)d_in[1];
  const float* w_out = (const float*)d_in[2];
  float* out = (float*)d_out;

  char* ws = (char*)d_ws;
  size_t off = 0;
  auto alloc = [&](size_t bytes) {
    char* p = ws + off;
    off += (bytes + 255) & ~(size_t)255;
    return p;
  };
  unsigned short* xb    = (unsigned short*)alloc((size_t)MR * Dc * 2);       // 16MB
  unsigned short* wqkvT = (unsigned short*)alloc((size_t)NQKV * Dc * 2);     // 24MB
  unsigned short* woutT = (unsigned short*)alloc((size_t)Dc * Dc * 2);       // 8MB
  unsigned short* qkvb  = (unsigned short*)alloc((size_t)MR * NQKV * 2);     // 48MB
  unsigned short* qhp   = (unsigned short*)alloc((size_t)MR * Dc * 2);       // 16MB
  unsigned short* khp   = (unsigned short*)alloc((size_t)MR * Dc * 2);       // 16MB
  unsigned short* vtp   = (unsigned short*)alloc((size_t)MR * Dc * 2);       // 16MB
  unsigned short* aop   = (unsigned short*)alloc((size_t)MR * Dc * 2);       // 16MB
  float2* cs            = (float2*)alloc((size_t)Tc * 64 * sizeof(float2));  // 1MB

  rope_table_kernel<<<Tc, 64, 0, stream>>>(cs);
  f32_to_bf16_kernel<<<(MR * Dc / 4 + 255) / 256, 256, 0, stream>>>(x, xb, MR * Dc);
  transpose_f32_bf16_kernel<<<dim3(NQKV / 32, Dc / 32), dim3(32, 8), 0, stream>>>(
      w_qkv, wqkvT, Dc, NQKV);
  transpose_f32_bf16_kernel<<<dim3(Dc / 32, Dc / 32), dim3(32, 8), 0, stream>>>(
      w_out, woutT, Dc, Dc);
  gemm_bt_kernel<unsigned short><<<(MR / 128) * (NQKV / 128), 256, 0, stream>>>(
      xb, wqkvT, qkvb, MR, NQKV, Dc);
  rope_apply_kernel<<<dim3(MR, Hc), 64, 0, stream>>>(qkvb, cs, qhp, khp);
  v_transpose_kernel<<<dim3(Tc / 32, HD / 32, 32), dim3(32, 8), 0, stream>>>(
      qkvb, vtp);
  attn_kernel<<<dim3(Tc / 128, 32), 256, 0, stream>>>(qhp, khp, vtp, aop);
  gemm_bt_kernel<float><<<(MR / 128) * (Dc / 128), 256, 0, stream>>>(
      aop, woutT, out, MR, Dc, Dc);
}

// Round 2
// 321.435 us; speedup vs baseline: 1.1083x; 1.1083x over previous
//
#include <hip/hip_runtime.h>

typedef __attribute__((ext_vector_type(8))) short bf16x8;
typedef __attribute__((ext_vector_type(4))) float f32x4;

#define DEVICE __device__ __forceinline__

static constexpr int Tc = 2048;     // seq len
static constexpr int Dc = 2048;     // model dim
static constexpr int Hc = 16;       // heads
static constexpr int HD = 128;      // head dim
static constexpr int MR = 4096;     // B*T rows
static constexpr int NQKV = 6144;   // 3*D

DEVICE float bf2f(unsigned short u) {
  unsigned int t = ((unsigned int)u) << 16;
  float f; __builtin_memcpy(&f, &t, 4); return f;
}
DEVICE unsigned short f2bf(float f) {
  unsigned int t; __builtin_memcpy(&t, &f, 4);
  unsigned int r = (t + 0x7fffu + ((t >> 16) & 1u)) >> 16;
  return (unsigned short)r;
}

DEVICE void async_cp16(const void* g, void* lds) {
  __builtin_amdgcn_global_load_lds((const __attribute__((address_space(1))) void*)g,
                                   (__attribute__((address_space(3))) void*)lds, 16, 0, 0);
}

// ---------------- RoPE cos/sin table: cs[t][j] = (cos, sin), j in [0,64) ----
__global__ void rope_table_kernel(float2* cs) {
  int t = blockIdx.x;
  int j = threadIdx.x;                   // 0..63
  float inv = powf(10000.0f, -(float)(2 * j) / 128.0f);
  float ang = (float)t * inv;
  cs[t * 64 + j] = make_float2(cosf(ang), sinf(ang));
}

// ---------------- fp32 -> bf16 elementwise (vectorized) ---------------------
__global__ void f32_to_bf16_kernel(const float* __restrict__ in,
                                   unsigned short* __restrict__ out, int n) {
  int i = (blockIdx.x * blockDim.x + threadIdx.x) * 4;
  if (i >= n) return;
  float4 v = *(const float4*)(in + i);
  ushort4 o;
  o.x = f2bf(v.x); o.y = f2bf(v.y); o.z = f2bf(v.z); o.w = f2bf(v.w);
  *(ushort4*)(out + i) = o;
}

// ---------------- transpose fp32 (R x C) -> bf16 (C x R) --------------------
__global__ void transpose_f32_bf16_kernel(const float* __restrict__ in,
                                          unsigned short* __restrict__ out,
                                          int R, int C) {
  __shared__ float tile[32][33];
  int c0 = blockIdx.x * 32, r0 = blockIdx.y * 32;
  int tx = threadIdx.x, ty = threadIdx.y;
#pragma unroll
  for (int i = 0; i < 4; ++i)
    tile[ty + i * 8][tx] = in[(size_t)(r0 + ty + i * 8) * C + c0 + tx];
  __syncthreads();
#pragma unroll
  for (int i = 0; i < 4; ++i)
    out[(size_t)(c0 + ty + i * 8) * R + r0 + tx] = f2bf(tile[tx][ty + i * 8]);
}

// ---------------- bf16 transpose of V slice: qkvb cols[4096..6144) ----------
// out vt[(bh*128 + d)*T + t]
__global__ void v_transpose_kernel(const unsigned short* __restrict__ qkvb,
                                   unsigned short* __restrict__ vt) {
  __shared__ unsigned short tile[32][33];
  int t0 = blockIdx.x * 32, d0 = blockIdx.y * 32, bh = blockIdx.z;
  int b = bh >> 4, h = bh & 15;
  int tx = threadIdx.x, ty = threadIdx.y;
#pragma unroll
  for (int i = 0; i < 4; ++i) {
    int t = t0 + ty + i * 8;
    tile[ty + i * 8][tx] =
        qkvb[(size_t)(b * Tc + t) * NQKV + 2 * Dc + h * HD + d0 + tx];
  }
  __syncthreads();
#pragma unroll
  for (int i = 0; i < 4; ++i) {
    int d = d0 + ty + i * 8;
    vt[(size_t)(bh * HD + d) * Tc + t0 + tx] = tile[tx][ty + i * 8];
  }
}

// ---------------- RoPE apply: qkvb -> qh, kh in (B,H,T,Hd) ------------------
__global__ void rope_apply_kernel(const unsigned short* __restrict__ qkvb,
                                  const float2* __restrict__ cs,
                                  unsigned short* __restrict__ qh,
                                  unsigned short* __restrict__ kh) {
  int m = blockIdx.x;          // b*T + t
  int h = blockIdx.y;
  int j = threadIdx.x;         // 0..63
  int t = m & (Tc - 1);
  int b = m >> 11;
  float2 c = cs[t * 64 + j];
  size_t base = (size_t)m * NQKV + h * HD;
  float q1 = bf2f(qkvb[base + j]);
  float q2 = bf2f(qkvb[base + j + 64]);
  float k1 = bf2f(qkvb[base + Dc + j]);
  float k2 = bf2f(qkvb[base + Dc + j + 64]);
  size_t ob = ((size_t)(b * Hc + h) * Tc + t) * HD;
  qh[ob + j]      = f2bf(q1 * c.x - q2 * c.y);
  qh[ob + j + 64] = f2bf(q2 * c.x + q1 * c.y);
  kh[ob + j]      = f2bf(k1 * c.x - k2 * c.y);
  kh[ob + j + 64] = f2bf(k2 * c.x + k1 * c.y);
}

// ---------------- bf16 GEMM, B^T input: C[m][n] = sum_k A[m][k]*Bt[n][k] ----
// 128x128 tile, BK=64, 4 waves, each wave 64x64 (4x4 frags of 16x16x32).
DEVICE void cstore(unsigned short* p, float v) { *p = f2bf(v); }
DEVICE void cstore(float* p, float v) { *p = v; }

template <typename OutT>
__global__ __launch_bounds__(256, 2)
void gemm_bt_kernel(const unsigned short* __restrict__ A,
                    const unsigned short* __restrict__ Bt,
                    OutT* __restrict__ C, int M, int N, int K) {
  __shared__ unsigned short As[128 * 64];
  __shared__ unsigned short Bs[128 * 64];

  int nbx = N >> 7;
  int nwg = gridDim.x;
  int wg = blockIdx.x;
  int cpx = nwg >> 3;                 // grids are multiples of 8 -> bijective
  wg = (wg & 7) * cpx + (wg >> 3);
  int by = wg / nbx, bx = wg - by * nbx;
  int m0 = by << 7, n0 = bx << 7;

  int tid = threadIdx.x, lane = tid & 63, wid = tid >> 6;
  int wm = (wid >> 1) << 6, wn = (wid & 1) << 6;

  f32x4 acc[4][4] = {};

  for (int k0 = 0; k0 < K; k0 += 64) {
    __syncthreads();
#pragma unroll
    for (int r = 0; r < 4; ++r) {
      int p = r * 4096 + wid * 1024 + lane * 16;   // byte offset in tile
      int row = p >> 7;
      int cb = (p & 127) ^ ((row & 7) << 4);       // pre-swizzled source col
      const char* ga = (const char*)A + ((size_t)(m0 + row) * K + k0) * 2 + cb;
      async_cp16(ga, (char*)As + r * 4096 + wid * 1024);
      const char* gb = (const char*)Bt + ((size_t)(n0 + row) * K + k0) * 2 + cb;
      async_cp16(gb, (char*)Bs + r * 4096 + wid * 1024);
    }
    __syncthreads();

#pragma unroll
    for (int ks = 0; ks < 2; ++ks) {
      bf16x8 af[4], bfr[4];
#pragma unroll
      for (int mi = 0; mi < 4; ++mi) {
        int row = wm + mi * 16 + (lane & 15);
        int cb = (ks * 64 + ((lane >> 4) << 4)) ^ ((row & 7) << 4);
        af[mi] = *(const bf16x8*)((const char*)As + row * 128 + cb);
      }
#pragma unroll
      for (int ni = 0; ni < 4; ++ni) {
        int row = wn + ni * 16 + (lane & 15);
        int cb = (ks * 64 + ((lane >> 4) << 4)) ^ ((row & 7) << 4);
        bfr[ni] = *(const bf16x8*)((const char*)Bs + row * 128 + cb);
      }
#pragma unroll
      for (int mi = 0; mi < 4; ++mi)
#pragma unroll
        for (int ni = 0; ni < 4; ++ni)
          acc[mi][ni] = __builtin_amdgcn_mfma_f32_16x16x32_bf16(
              af[mi], bfr[ni], acc[mi][ni], 0, 0, 0);
    }
  }

#pragma unroll
  for (int mi = 0; mi < 4; ++mi)
#pragma unroll
    for (int ni = 0; ni < 4; ++ni)
#pragma unroll
      for (int r = 0; r < 4; ++r) {
        int row = m0 + wm + mi * 16 + ((lane >> 4) << 2) + r;
        int col = n0 + wn + ni * 16 + (lane & 15);
        cstore(C + (size_t)row * N + col, acc[mi][ni][r]);
      }
}

// ---------------- causal flash attention ------------------------------------
// BQ=64, 32 q-tiles paired (p, 31-p) -> uniform 33 k-tiles per block.
// grid (16, B*H), 4 waves; each wave owns 16 q-rows. K/V double-buffered in
// LDS via global_load_lds (pre-swizzled source), staged t+1 overlapped with
// compute of t (minimal 2-phase schedule).
__global__ __launch_bounds__(256, 2)
void attn_kernel(const unsigned short* __restrict__ qh,
                 const unsigned short* __restrict__ kh,
                 const unsigned short* __restrict__ vt,
                 unsigned short* __restrict__ ao) {
  const float scale = 0.08838834764831845f;  // 1/sqrt(128)
  int pairp = blockIdx.x;                    // 0..15
  int bh = blockIdx.y;
  int b = bh >> 4, h = bh & 15;

  __shared__ unsigned short Ks[2][64 * 128];   // 2 x 16KB, 256B rows, swizzled
  __shared__ unsigned short Vs[2][128 * 64];   // 2 x 16KB, V^T rows=d, 128B
  __shared__ unsigned short Ps[4][16 * 64];    // 8KB, per-wave P, 128B rows

  int tid = threadIdx.x, lane = tid & 63, wid = tid >> 6;

  const unsigned short* Kg = kh + (size_t)bh * Tc * HD;
  const unsigned short* Vg = vt + (size_t)bh * HD * Tc;

  auto stage = [&](int kt, int buf) {
#pragma unroll
    for (int r = 0; r < 4; ++r) {
      int p = r * 4096 + wid * 1024 + lane * 16;
      {
        int row = p >> 8, cb = p & 255;
        const char* g = (const char*)Kg + ((size_t)(kt * 64 + row)) * 256 +
                        (cb ^ ((row & 7) << 4));
        async_cp16(g, (char*)&Ks[buf][0] + r * 4096 + wid * 1024);
      }
      {
        int d = p >> 7, cb = p & 127;
        const char* g = (const char*)Vg + (size_t)d * (Tc * 2) + kt * 128 +
                        (cb ^ ((d & 7) << 4));
        async_cp16(g, (char*)&Vs[buf][0] + r * 4096 + wid * 1024);
      }
    }
  };

#pragma unroll 1
  for (int pass = 0; pass < 2; ++pass) {
    int qt = pass ? (31 - pairp) : pairp;
    const unsigned short* Qg = qh + ((size_t)bh * Tc + qt * 64) * HD;

    // Q fragments direct from global (no LDS round-trip)
    bf16x8 qf[4];
#pragma unroll
    for (int ks = 0; ks < 4; ++ks) {
      int row = wid * 16 + (lane & 15);
      qf[ks] = *(const bf16x8*)((const char*)Qg + row * 256 + ks * 64 +
                                ((lane >> 4) << 4));
    }

    f32x4 oacc[8] = {};
    float mrow[4], lrow[4];
#pragma unroll
    for (int r = 0; r < 4; ++r) { mrow[r] = -1e30f; lrow[r] = 0.f; }

    int nkt = qt + 1;
    __syncthreads();     // pass boundary: prior pass's LDS reads done
    stage(0, 0);
    int cur = 0;
#pragma unroll 1
    for (int kt = 0; kt < nkt; ++kt) {
      __syncthreads();   // drains vmcnt -> Ks/Vs[cur] ready; prev reads done
      if (kt + 1 < nkt) stage(kt + 1, cur ^ 1);  // overlap with compute below

      // S = Q K^T  (16 x 64)
      f32x4 sacc[4] = {};
      __builtin_amdgcn_s_setprio(1);
#pragma unroll
      for (int ks = 0; ks < 4; ++ks) {
#pragma unroll
        for (int ni = 0; ni < 4; ++ni) {
          int row = ni * 16 + (lane & 15);
          int cb = (ks * 64 + ((lane >> 4) << 4)) ^ ((row & 7) << 4);
          bf16x8 kf = *(const bf16x8*)((const char*)&Ks[cur][0] + row * 256 + cb);
          sacc[ni] = __builtin_amdgcn_mfma_f32_16x16x32_bf16(qf[ks], kf,
                                                             sacc[ni], 0, 0, 0);
        }
      }
      __builtin_amdgcn_s_setprio(0);

      // online softmax: 4 lane-groups each own 4 rows
      bool diag = (kt == qt);
      float pvv[4][4];
      float fsc[4];
#pragma unroll
      for (int r = 0; r < 4; ++r) {
        int qrow = qt * 64 + wid * 16 + ((lane >> 4) << 2) + r;
        float sv[4];
        float mx = -1e30f;
#pragma unroll
        for (int ni = 0; ni < 4; ++ni) {
          float s = sacc[ni][r] * scale;
          if (diag) {
            int kcol = kt * 64 + ni * 16 + (lane & 15);
            if (kcol > qrow) s = -1e30f;
          }
          sv[ni] = s;
          mx = fmaxf(mx, s);
        }
        mx = fmaxf(mx, __shfl_xor(mx, 1));
        mx = fmaxf(mx, __shfl_xor(mx, 2));
        mx = fmaxf(mx, __shfl_xor(mx, 4));
        mx = fmaxf(mx, __shfl_xor(mx, 8));
        float mnew = fmaxf(mrow[r], mx);
        float f = __expf(mrow[r] - mnew);
        mrow[r] = mnew;
        float ls = 0.f;
#pragma unroll
        for (int ni = 0; ni < 4; ++ni) {
          float pp = __expf(sv[ni] - mnew);
          pvv[ni][r] = pp;
          ls += pp;
        }
        ls += __shfl_xor(ls, 1);
        ls += __shfl_xor(ls, 2);
        ls += __shfl_xor(ls, 4);
        ls += __shfl_xor(ls, 8);
        lrow[r] = lrow[r] * f + ls;
        fsc[r] = f;
      }
      // rescale O (skip when running max unchanged for all rows)
      bool need = (fsc[0] < 1.f) | (fsc[1] < 1.f) | (fsc[2] < 1.f) | (fsc[3] < 1.f);
      if (__any(need)) {
#pragma unroll
        for (int nj = 0; nj < 8; ++nj)
#pragma unroll
          for (int r = 0; r < 4; ++r) oacc[nj][r] *= fsc[r];
      }

      // write P (bf16) to per-wave LDS, swizzled
#pragma unroll
      for (int ni = 0; ni < 4; ++ni)
#pragma unroll
        for (int r = 0; r < 4; ++r) {
          int row = ((lane >> 4) << 2) + r;
          int colb = (ni * 16 + (lane & 15)) * 2;
          *(unsigned short*)((char*)&Ps[wid][0] + row * 128 +
                             (colb ^ ((row & 7) << 4))) = f2bf(pvv[ni][r]);
        }

      // O += P @ V  (same-wave LDS RAW; compiler inserts lgkmcnt waits)
      __builtin_amdgcn_s_setprio(1);
#pragma unroll
      for (int ks = 0; ks < 2; ++ks) {
        int prow = lane & 15;
        int pcb = (ks * 64 + ((lane >> 4) << 4)) ^ ((prow & 7) << 4);
        bf16x8 pf = *(const bf16x8*)((const char*)&Ps[wid][0] + prow * 128 + pcb);
#pragma unroll
        for (int nj = 0; nj < 8; ++nj) {
          int vrow = nj * 16 + (lane & 15);
          int vcb = (ks * 64 + ((lane >> 4) << 4)) ^ ((vrow & 7) << 4);
          bf16x8 vf = *(const bf16x8*)((const char*)&Vs[cur][0] + vrow * 128 + vcb);
          oacc[nj] = __builtin_amdgcn_mfma_f32_16x16x32_bf16(pf, vf,
                                                             oacc[nj], 0, 0, 0);
        }
      }
      __builtin_amdgcn_s_setprio(0);
      cur ^= 1;
    }

    // epilogue: O / l -> ao (B,T,D) bf16
    float inv[4];
#pragma unroll
    for (int r = 0; r < 4; ++r) inv[r] = 1.f / lrow[r];
#pragma unroll
    for (int nj = 0; nj < 8; ++nj)
#pragma unroll
      for (int r = 0; r < 4; ++r) {
        int trow = qt * 64 + wid * 16 + ((lane >> 4) << 2) + r;
        int col = nj * 16 + (lane & 15);
        ao[((size_t)(b * Tc + trow)) * Dc + h * HD + col] =
            f2bf(oacc[nj][r] * inv[r]);
      }
  }
}

// ---------------- launcher --------------------------------------------------
extern "C" void kernel_launch(void* const* d_in, const int* in_sizes, int n_in,
                              void* d_out, int out_size, void* d_ws,
                              size_t ws_size, hipStream_t stream) {
  const float* x = (const float*)d_in[0];
  const float* w_qkv = (const float*)d_in[1];
  const float* w_out = (const float*)d_in[2];
  float* out = (float*)d_out;

  char* ws = (char*)d_ws;
  size_t off = 0;
  auto alloc = [&](size_t bytes) {
    char* p = ws + off;
    off += (bytes + 255) & ~(size_t)255;
    return p;
  };
  unsigned short* xb    = (unsigned short*)alloc((size_t)MR * Dc * 2);       // 16MB
  unsigned short* wqkvT = (unsigned short*)alloc((size_t)NQKV * Dc * 2);     // 24MB
  unsigned short* woutT = (unsigned short*)alloc((size_t)Dc * Dc * 2);       // 8MB
  unsigned short* qkvb  = (unsigned short*)alloc((size_t)MR * NQKV * 2);     // 48MB
  unsigned short* qhp   = (unsigned short*)alloc((size_t)MR * Dc * 2);       // 16MB
  unsigned short* khp   = (unsigned short*)alloc((size_t)MR * Dc * 2);       // 16MB
  unsigned short* vtp   = (unsigned short*)alloc((size_t)MR * Dc * 2);       // 16MB
  unsigned short* aop   = (unsigned short*)alloc((size_t)MR * Dc * 2);       // 16MB
  float2* cs            = (float2*)alloc((size_t)Tc * 64 * sizeof(float2));  // 1MB

  rope_table_kernel<<<Tc, 64, 0, stream>>>(cs);
  f32_to_bf16_kernel<<<(MR * Dc / 4 + 255) / 256, 256, 0, stream>>>(x, xb, MR * Dc);
  transpose_f32_bf16_kernel<<<dim3(NQKV / 32, Dc / 32), dim3(32, 8), 0, stream>>>(
      w_qkv, wqkvT, Dc, NQKV);
  transpose_f32_bf16_kernel<<<dim3(Dc / 32, Dc / 32), dim3(32, 8), 0, stream>>>(
      w_out, woutT, Dc, Dc);
  gemm_bt_kernel<unsigned short><<<(MR / 128) * (NQKV / 128), 256, 0, stream>>>(
      xb, wqkvT, qkvb, MR, NQKV, Dc);
  rope_apply_kernel<<<dim3(MR, Hc), 64, 0, stream>>>(qkvb, cs, qhp, khp);
  v_transpose_kernel<<<dim3(Tc / 32, HD / 32, 32), dim3(32, 8), 0, stream>>>(
      qkvb, vtp);
  attn_kernel<<<dim3(16, 32), 256, 0, stream>>>(qhp, khp, vtp, aop);
  gemm_bt_kernel<float><<<(MR / 128) * (Dc / 128), 256, 0, stream>>>(
      aop, woutT, out, MR, Dc, Dc);
}